// Round 4
// baseline (547.390 us; speedup 1.0000x reference)
//
#include <hip/hip_runtime.h>
#include <math.h>

// Problem constants
#define K_KP 15
#define DZB  64
#define HH   192
#define WW   192
#define CH   79                    // K_KP + DZB
#define BATCH 32
#define HWPIX (HH*WW)              // 36864
#define GROUPS_PER_BATCH (HWPIX/4) // 9216 (group = 4 consecutive pixels = 79 float4s)
#define NGROUPS (BATCH*GROUPS_PER_BATCH) // 294912
#define BLKA 256
#define NBLKA (NGROUPS/BLKA)       // 1152
#define BLOCKS_PER_BATCH (GROUPS_PER_BATCH/BLKA) // 36

typedef const __attribute__((address_space(1))) void* gas_t;
typedef __attribute__((address_space(3))) void* las_t;

// ---------------------------------------------------------------------------
// Kernel A: xy-branch softmax statistics. (bit-identical to round 2)
// PROBE NOTE: launched 3x this round to measure kA's true cost from the
// dur_us delta (kA is idempotent; partials are rewritten identically).
// ---------------------------------------------------------------------------
__global__ __launch_bounds__(BLKA) void kA(const float* __restrict__ feat,
                                           float* __restrict__ partials) {
  __shared__ __align__(16) char smem[73728];   // 4 waves * 64 groups * 288 B
  const int tid  = threadIdx.x;
  const int lane = tid & 63;
  const int wv   = tid >> 6;
  const int gBlk  = blockIdx.x * BLKA;
  const int gWave = gBlk + wv * 64;

  // ---- async stage: 18 passes of global_load_lds dwordx4 (wave-private) ----
  {
    const char* fb = (const char*)feat + (size_t)gWave * 1264;
    char* lw = smem + wv * 18432;
    int g = (lane >= 54) ? 3 : (lane >= 36) ? 2 : (lane >= 18) ? 1 : 0;
    int s = lane - g * 18;
#pragma unroll
    for (int j = 0; j < 18; ++j) {
      const int seg = (s < 4) ? 0 : (s < 9) ? 1 : (s < 14) ? 2 : 3;
      const char* src = fb + (size_t)g * 1264 + (size_t)(s * 16 + seg * 240);
      __builtin_amdgcn_global_load_lds((gas_t)src, (las_t)(lw + j * 1024), 16, 0, 0);
      s += 10; g += 3;
      if (s >= 18) { s -= 18; g += 1; }
    }
  }
  asm volatile("s_waitcnt vmcnt(0)" ::: "memory");

  // ---- per-thread compute: thread owns group gBlk+tid (staged at lane*288) ----
  const int gg  = (gBlk + tid) % GROUPS_PER_BATCH;
  const int row = gg / 48;
  const int w0  = (gg - row * 48) * 4;
  const float hx = (float)row * 0.01f;

  const float4* __restrict__ G = (const float4*)(smem + wv * 18432 + lane * 288);

  float aS[15], aW[15], aW2[15];
#pragma unroll
  for (int i = 0; i < 15; i++) { aS[i] = 0.f; aW[i] = 0.f; aW2[i] = 0.f; }

  float wx, e, t;
#define ACC(c, val) { e = __expf(val); aS[c] += e; t = e * wx; aW[c] += t; aW2[c] += t * wx; }
  {
    float4 v0 = G[0], v1 = G[1], v2 = G[2], v3 = G[3];
    wx = (float)w0 * 0.01f;
    ACC(0,v0.x) ACC(1,v0.y) ACC(2,v0.z) ACC(3,v0.w)
    ACC(4,v1.x) ACC(5,v1.y) ACC(6,v1.z) ACC(7,v1.w)
    ACC(8,v2.x) ACC(9,v2.y) ACC(10,v2.z) ACC(11,v2.w)
    ACC(12,v3.x) ACC(13,v3.y) ACC(14,v3.z)
  }
  {
    float4 u0 = G[4], u1 = G[5], u2 = G[6], u3 = G[7], u4 = G[8];
    wx = (float)(w0+1) * 0.01f;
    ACC(0,u0.w)
    ACC(1,u1.x) ACC(2,u1.y) ACC(3,u1.z) ACC(4,u1.w)
    ACC(5,u2.x) ACC(6,u2.y) ACC(7,u2.z) ACC(8,u2.w)
    ACC(9,u3.x) ACC(10,u3.y) ACC(11,u3.z) ACC(12,u3.w)
    ACC(13,u4.x) ACC(14,u4.y)
  }
  {
    float4 x0 = G[9], x1 = G[10], x2 = G[11], x3 = G[12], x4 = G[13];
    wx = (float)(w0+2) * 0.01f;
    ACC(0,x0.z) ACC(1,x0.w)
    ACC(2,x1.x) ACC(3,x1.y) ACC(4,x1.z) ACC(5,x1.w)
    ACC(6,x2.x) ACC(7,x2.y) ACC(8,x2.z) ACC(9,x2.w)
    ACC(10,x3.x) ACC(11,x3.y) ACC(12,x3.z) ACC(13,x3.w)
    ACC(14,x4.x)
  }
  {
    float4 y0 = G[14], y1 = G[15], y2 = G[16], y3 = G[17];
    wx = (float)(w0+3) * 0.01f;
    ACC(0,y0.y) ACC(1,y0.z) ACC(2,y0.w)
    ACC(3,y1.x) ACC(4,y1.y) ACC(5,y1.z) ACC(6,y1.w)
    ACC(7,y2.x) ACC(8,y2.y) ACC(9,y2.z) ACC(10,y2.w)
    ACC(11,y3.x) ACC(12,y3.y) ACC(13,y3.z) ACC(14,y3.w)
  }
#undef ACC

  const float hx2 = hx * hx;

  // ---- block reduce (aliases the staging LDS; identical order) ----
  float (*red)[BLKA + 1] = (float (*)[BLKA + 1])smem;
  float (*red2)[8]       = (float (*)[8])(smem + 30 * (BLKA + 1) * sizeof(float));

#pragma unroll
  for (int chunk = 0; chunk < 2; ++chunk) {
    __syncthreads();
#pragma unroll
    for (int j = 0; j < 30; j++) {
      const int J = chunk * 30 + j;
      const int k = J >> 2, s = J & 3;
      float v = (s == 0) ? aS[k]
              : (s == 1) ? hx * aS[k]
              : (s == 2) ? aW[k]
                         : fmaf(hx2, aS[k], aW2[k]);
      red[j][tid] = v;
    }
    __syncthreads();
    if (tid < 240) {
      const int r = tid >> 3, sg = tid & 7;
      float a = 0.f;
#pragma unroll
      for (int i = 0; i < 32; i++) a += red[r][sg * 32 + i];
      red2[r][sg] = a;
    }
    __syncthreads();
    if (tid < 30) {
      float a = 0.f;
#pragma unroll
      for (int i = 0; i < 8; i++) a += red2[tid][i];
      partials[blockIdx.x * 60 + chunk * 30 + tid] = a;
    }
  }
}

// ---------------------------------------------------------------------------
// Kernel B: single block, final reduce + z-branch + reweight. (unchanged)
// ---------------------------------------------------------------------------
__global__ __launch_bounds__(512) void kB(const float* __restrict__ partials,
                                          const float* __restrict__ gt,
                                          const float* __restrict__ feat,
                                          float* __restrict__ out) {
  const int tid = threadIdx.x;
  __shared__ float Lxy[480], Lz[480], sGtz[480];
  __shared__ int   sPix[480];
  __shared__ float lbx[15], lbz[15];

  const int b = tid / 15;
  const int k = tid - b * 15;

  float locz = 0.f, varz = 0.f;
  if (tid < 480) {
    float S = 0.f, Sh = 0.f, Sw = 0.f, Sr = 0.f;
    for (int j = 0; j < BLOCKS_PER_BATCH; ++j) {
      const float4 p = *(const float4*)(partials +
                        ((size_t)(b * BLOCKS_PER_BATCH + j) * 60 + k * 4));
      S += p.x; Sh += p.y; Sw += p.z; Sr += p.w;
    }
    const float lx = Sh / S, ly = Sw / S;
    const float var = Sr / S - (lx * lx + ly * ly);

    const float maxloc = 191.0f * 0.01f;
    const float gtx = fminf(gt[(b * 15 + k) * 3 + 0], maxloc);
    const float gty = fminf(gt[(b * 15 + k) * 3 + 1], maxloc);
    const float gtz = fminf(gt[(b * 15 + k) * 3 + 2], 6.3f);

    const float dx = lx - gtx, dy = ly - gty;
    Lxy[tid] = dx * dx + dy * dy + var;

    int ix = (int)rintf(gtx / 0.01f); ix = min(max(ix, 0), HH - 1);
    int iy = (int)rintf(gty / 0.01f); iy = min(max(iy, 0), WW - 1);
    sPix[tid] = ix * WW + iy;
    sGtz[tid] = gtz;

    const float* fz = feat + (size_t)(b * HWPIX + ix * WW + iy) * CH + K_KP;
    float Sz = 0.f, S1 = 0.f, S2 = 0.f;
#pragma unroll
    for (int c = 0; c < DZB; ++c) {
      const float ez = __expf(fz[c]);
      const float lz = (float)c * 0.1f;
      Sz += ez;
      S1 += ez * lz;
      S2 += ez * lz * lz;
    }
    locz = S1 / Sz;
    varz = S2 / Sz - locz * locz;
  }
  __syncthreads();
  if (tid < 480) {
    const int pix = sPix[tid];
    float ge = sGtz[tid];
    for (int k2 = k + 1; k2 < 15; ++k2)
      if (sPix[b * 15 + k2] == pix) ge = sGtz[b * 15 + k2];
    const float d = locz - ge;
    Lz[tid] = d * d + varz;
  }
  __syncthreads();
  if (tid < 15) {
    float a = 0.f, c = 0.f;
    for (int b2 = 0; b2 < BATCH; ++b2) {
      a += Lxy[b2 * 15 + tid];
      c += Lz[b2 * 15 + tid];
    }
    lbx[tid] = a; lbz[tid] = c;
  }
  __syncthreads();
  if (tid == 0) {
    float sx = 0.f, sz = 0.f;
    for (int k2 = 0; k2 < 15; ++k2) { sx += lbx[k2]; sz += lbz[k2]; }
    sx = (sx + 0.001f) / 15.f;
    sz = (sz + 0.001f) / 15.f;
    float L = 0.f;
    for (int k2 = 0; k2 < 15; ++k2)
      L += lbx[k2] * (lbx[k2] / sx) + lbz[k2] * (lbz[k2] / sz);
    out[0] = L;
  }
}

extern "C" void kernel_launch(void* const* d_in, const int* in_sizes, int n_in,
                              void* d_out, int out_size, void* d_ws, size_t ws_size,
                              hipStream_t stream) {
  const float* feat = (const float*)d_in[0];   // [32,192,192,79] f32
  const float* gt   = (const float*)d_in[1];   // [32,15,3] f32
  float* out        = (float*)d_out;           // scalar f32
  float* partials   = (float*)d_ws;            // NBLKA*60 floats = 276,480 B

  // PROBE: kA launched 3x (idempotent). dur_us delta vs round 2 (474.6) = 2*kA.
  hipLaunchKernelGGL(kA, dim3(NBLKA), dim3(BLKA), 0, stream, feat, partials);
  hipLaunchKernelGGL(kA, dim3(NBLKA), dim3(BLKA), 0, stream, feat, partials);
  hipLaunchKernelGGL(kA, dim3(NBLKA), dim3(BLKA), 0, stream, feat, partials);
  hipLaunchKernelGGL(kB, dim3(1), dim3(512), 0, stream, partials, gt, feat, out);
}

// Round 5
// 473.897 us; speedup vs baseline: 1.1551x; 1.1551x over previous
//
#include <hip/hip_runtime.h>
#include <math.h>

// Problem constants
#define K_KP 15
#define DZB  64
#define HH   192
#define WW   192
#define CH   79                    // K_KP + DZB
#define BATCH 32
#define HWPIX (HH*WW)              // 36864
#define GROUPS_PER_BATCH (HWPIX/4) // 9216 (group = 4 consecutive pixels = 79 float4s)
#define NGROUPS (BATCH*GROUPS_PER_BATCH) // 294912
#define BLKA 256
#define NBLKA (NGROUPS/BLKA)       // 1152
#define BLOCKS_PER_BATCH (GROUPS_PER_BATCH/BLKA) // 36

typedef const __attribute__((address_space(1))) void* gas_t;
typedef __attribute__((address_space(3))) void* las_t;

// ---------------------------------------------------------------------------
// Kernel A: xy-branch softmax statistics.
// Measured (round-4 3x probe): 36.4 us, ~234 MB line-granularity fetch at
// ~6.4 TB/s -> at the HBM achievable ceiling for its minimal fetch set.
// Per wave: 64 four-pixel groups; the 18 float4 slots covering channels
// 0..14 of 4 pixels are staged to LDS via async global_load_lds dwordx4
// (slots-major lane mapping => ~18 lines/instr). LDS is wave-private.
// ---------------------------------------------------------------------------
__global__ __launch_bounds__(BLKA) void kA(const float* __restrict__ feat,
                                           float* __restrict__ partials) {
  __shared__ __align__(16) char smem[73728];   // 4 waves * 64 groups * 288 B
  const int tid  = threadIdx.x;
  const int lane = tid & 63;
  const int wv   = tid >> 6;
  const int gBlk  = blockIdx.x * BLKA;
  const int gWave = gBlk + wv * 64;

  // ---- async stage: 18 passes of global_load_lds dwordx4 (wave-private) ----
  {
    const char* fb = (const char*)feat + (size_t)gWave * 1264;
    char* lw = smem + wv * 18432;
    int g = (lane >= 54) ? 3 : (lane >= 36) ? 2 : (lane >= 18) ? 1 : 0;
    int s = lane - g * 18;
#pragma unroll
    for (int j = 0; j < 18; ++j) {
      const int seg = (s < 4) ? 0 : (s < 9) ? 1 : (s < 14) ? 2 : 3;
      const char* src = fb + (size_t)g * 1264 + (size_t)(s * 16 + seg * 240);
      __builtin_amdgcn_global_load_lds((gas_t)src, (las_t)(lw + j * 1024), 16, 0, 0);
      s += 10; g += 3;
      if (s >= 18) { s -= 18; g += 1; }
    }
  }
  asm volatile("s_waitcnt vmcnt(0)" ::: "memory");

  // ---- per-thread compute: thread owns group gBlk+tid (staged at lane*288) ----
  const int gg  = (gBlk + tid) % GROUPS_PER_BATCH;
  const int row = gg / 48;
  const int w0  = (gg - row * 48) * 4;
  const float hx = (float)row * 0.01f;

  const float4* __restrict__ G = (const float4*)(smem + wv * 18432 + lane * 288);

  float aS[15], aW[15], aW2[15];
#pragma unroll
  for (int i = 0; i < 15; i++) { aS[i] = 0.f; aW[i] = 0.f; aW2[i] = 0.f; }

  float wx, e, t;
#define ACC(c, val) { e = __expf(val); aS[c] += e; t = e * wx; aW[c] += t; aW2[c] += t * wx; }
  {
    float4 v0 = G[0], v1 = G[1], v2 = G[2], v3 = G[3];
    wx = (float)w0 * 0.01f;
    ACC(0,v0.x) ACC(1,v0.y) ACC(2,v0.z) ACC(3,v0.w)
    ACC(4,v1.x) ACC(5,v1.y) ACC(6,v1.z) ACC(7,v1.w)
    ACC(8,v2.x) ACC(9,v2.y) ACC(10,v2.z) ACC(11,v2.w)
    ACC(12,v3.x) ACC(13,v3.y) ACC(14,v3.z)
  }
  {
    float4 u0 = G[4], u1 = G[5], u2 = G[6], u3 = G[7], u4 = G[8];
    wx = (float)(w0+1) * 0.01f;
    ACC(0,u0.w)
    ACC(1,u1.x) ACC(2,u1.y) ACC(3,u1.z) ACC(4,u1.w)
    ACC(5,u2.x) ACC(6,u2.y) ACC(7,u2.z) ACC(8,u2.w)
    ACC(9,u3.x) ACC(10,u3.y) ACC(11,u3.z) ACC(12,u3.w)
    ACC(13,u4.x) ACC(14,u4.y)
  }
  {
    float4 x0 = G[9], x1 = G[10], x2 = G[11], x3 = G[12], x4 = G[13];
    wx = (float)(w0+2) * 0.01f;
    ACC(0,x0.z) ACC(1,x0.w)
    ACC(2,x1.x) ACC(3,x1.y) ACC(4,x1.z) ACC(5,x1.w)
    ACC(6,x2.x) ACC(7,x2.y) ACC(8,x2.z) ACC(9,x2.w)
    ACC(10,x3.x) ACC(11,x3.y) ACC(12,x3.z) ACC(13,x3.w)
    ACC(14,x4.x)
  }
  {
    float4 y0 = G[14], y1 = G[15], y2 = G[16], y3 = G[17];
    wx = (float)(w0+3) * 0.01f;
    ACC(0,y0.y) ACC(1,y0.z) ACC(2,y0.w)
    ACC(3,y1.x) ACC(4,y1.y) ACC(5,y1.z) ACC(6,y1.w)
    ACC(7,y2.x) ACC(8,y2.y) ACC(9,y2.z) ACC(10,y2.w)
    ACC(11,y3.x) ACC(12,y3.y) ACC(13,y3.z) ACC(14,y3.w)
  }
#undef ACC

  const float hx2 = hx * hx;

  // ---- block reduce (aliases the staging LDS; deterministic order) ----
  float (*red)[BLKA + 1] = (float (*)[BLKA + 1])smem;
  float (*red2)[8]       = (float (*)[8])(smem + 30 * (BLKA + 1) * sizeof(float));

#pragma unroll
  for (int chunk = 0; chunk < 2; ++chunk) {
    __syncthreads();
#pragma unroll
    for (int j = 0; j < 30; j++) {
      const int J = chunk * 30 + j;
      const int k = J >> 2, s = J & 3;
      float v = (s == 0) ? aS[k]
              : (s == 1) ? hx * aS[k]
              : (s == 2) ? aW[k]
                         : fmaf(hx2, aS[k], aW2[k]);
      red[j][tid] = v;
    }
    __syncthreads();
    if (tid < 240) {
      const int r = tid >> 3, sg = tid & 7;
      float a = 0.f;
#pragma unroll
      for (int i = 0; i < 32; i++) a += red[r][sg * 32 + i];
      red2[r][sg] = a;
    }
    __syncthreads();
    if (tid < 30) {
      float a = 0.f;
#pragma unroll
      for (int i = 0; i < 8; i++) a += red2[tid][i];
      partials[blockIdx.x * 60 + chunk * 30 + tid] = a;
    }
  }
}

// ---------------------------------------------------------------------------
// Kernel B: single block, final reduce + z-branch + reweight.
// ---------------------------------------------------------------------------
__global__ __launch_bounds__(512) void kB(const float* __restrict__ partials,
                                          const float* __restrict__ gt,
                                          const float* __restrict__ feat,
                                          float* __restrict__ out) {
  const int tid = threadIdx.x;
  __shared__ float Lxy[480], Lz[480], sGtz[480];
  __shared__ int   sPix[480];
  __shared__ float lbx[15], lbz[15];

  const int b = tid / 15;
  const int k = tid - b * 15;

  float locz = 0.f, varz = 0.f;
  if (tid < 480) {
    float S = 0.f, Sh = 0.f, Sw = 0.f, Sr = 0.f;
    for (int j = 0; j < BLOCKS_PER_BATCH; ++j) {
      const float4 p = *(const float4*)(partials +
                        ((size_t)(b * BLOCKS_PER_BATCH + j) * 60 + k * 4));
      S += p.x; Sh += p.y; Sw += p.z; Sr += p.w;
    }
    const float lx = Sh / S, ly = Sw / S;
    const float var = Sr / S - (lx * lx + ly * ly);

    const float maxloc = 191.0f * 0.01f;
    const float gtx = fminf(gt[(b * 15 + k) * 3 + 0], maxloc);
    const float gty = fminf(gt[(b * 15 + k) * 3 + 1], maxloc);
    const float gtz = fminf(gt[(b * 15 + k) * 3 + 2], 6.3f);

    const float dx = lx - gtx, dy = ly - gty;
    Lxy[tid] = dx * dx + dy * dy + var;

    int ix = (int)rintf(gtx / 0.01f); ix = min(max(ix, 0), HH - 1);
    int iy = (int)rintf(gty / 0.01f); iy = min(max(iy, 0), WW - 1);
    sPix[tid] = ix * WW + iy;
    sGtz[tid] = gtz;

    const float* fz = feat + (size_t)(b * HWPIX + ix * WW + iy) * CH + K_KP;
    float Sz = 0.f, S1 = 0.f, S2 = 0.f;
#pragma unroll
    for (int c = 0; c < DZB; ++c) {
      const float ez = __expf(fz[c]);
      const float lz = (float)c * 0.1f;
      Sz += ez;
      S1 += ez * lz;
      S2 += ez * lz * lz;
    }
    locz = S1 / Sz;
    varz = S2 / Sz - locz * locz;
  }
  __syncthreads();
  if (tid < 480) {
    const int pix = sPix[tid];
    float ge = sGtz[tid];
    for (int k2 = k + 1; k2 < 15; ++k2)
      if (sPix[b * 15 + k2] == pix) ge = sGtz[b * 15 + k2];
    const float d = locz - ge;
    Lz[tid] = d * d + varz;
  }
  __syncthreads();
  if (tid < 15) {
    float a = 0.f, c = 0.f;
    for (int b2 = 0; b2 < BATCH; ++b2) {
      a += Lxy[b2 * 15 + tid];
      c += Lz[b2 * 15 + tid];
    }
    lbx[tid] = a; lbz[tid] = c;
  }
  __syncthreads();
  if (tid == 0) {
    float sx = 0.f, sz = 0.f;
    for (int k2 = 0; k2 < 15; ++k2) { sx += lbx[k2]; sz += lbz[k2]; }
    sx = (sx + 0.001f) / 15.f;
    sz = (sz + 0.001f) / 15.f;
    float L = 0.f;
    for (int k2 = 0; k2 < 15; ++k2)
      L += lbx[k2] * (lbx[k2] / sx) + lbz[k2] * (lbz[k2] / sz);
    out[0] = L;
  }
}

extern "C" void kernel_launch(void* const* d_in, const int* in_sizes, int n_in,
                              void* d_out, int out_size, void* d_ws, size_t ws_size,
                              hipStream_t stream) {
  const float* feat = (const float*)d_in[0];   // [32,192,192,79] f32
  const float* gt   = (const float*)d_in[1];   // [32,15,3] f32
  float* out        = (float*)d_out;           // scalar f32
  float* partials   = (float*)d_ws;            // NBLKA*60 floats = 276,480 B

  hipLaunchKernelGGL(kA, dim3(NBLKA), dim3(BLKA), 0, stream, feat, partials);
  hipLaunchKernelGGL(kB, dim3(1), dim3(512), 0, stream, partials, gt, feat, out);
}